// Round 5
// baseline (477.293 us; speedup 1.0000x reference)
//
#include <hip/hip_runtime.h>
#include <stdint.h>

#define NSCENE 16
#define NPED 32
#define NB_TOT 512
#define HD 64
#define ED 64
#define D1 8192
#define BOTN 1024
#define ASTR 72  // A-tile LDS row stride in shorts (144B): 16B-aligned, 4-bank rotate/row
#define BSTR 72  // B-tile LDS row stride in shorts

typedef unsigned short ushort_t;
typedef __attribute__((ext_vector_type(4))) float f32x4;
typedef __attribute__((ext_vector_type(8))) __bf16 bf16x8;  // gfx950 mfma operand (V8y)
typedef __attribute__((ext_vector_type(4))) unsigned int u32x4;

__device__ __forceinline__ float bf2f(ushort_t u) {
  union { unsigned int i; float f; } x;
  x.i = ((unsigned int)u) << 16;
  return x.f;
}

__device__ __forceinline__ ushort_t f2bf(float f) {
  union { float f; unsigned int i; } x;
  x.f = f;
  unsigned int u = x.i + 0x7fffu + ((x.i >> 16) & 1u);
  return (ushort_t)(u >> 16);
}

// pack two f32 -> two bf16 (lo in bits [15:0]) — portable RNE
__device__ __forceinline__ unsigned int f2bf2(float lo, float hi) {
  return (unsigned int)f2bf(lo) | ((unsigned int)f2bf(hi) << 16);
}

// ---------------------------------------------------------------------------
// k_detect: decide whether float inputs are fp32 (expected) or bf16.
// Sample W1's even-indexed ushorts: fp32 -> low mantissa halves, random
// exponent field (~14% in sane range); bf16 -> genuine values (~100% sane).
// Also produce canonical fp32 copies of end_pos and b2.
// ---------------------------------------------------------------------------
__global__ __launch_bounds__(256) void k_detect(
    const void* __restrict__ W1v, const void* __restrict__ end_posv,
    const void* __restrict__ b2v, int* __restrict__ flag,
    float* __restrict__ epf, float* __restrict__ b2f) {
  __shared__ int cnt[256];
  __shared__ int isbf_s;
  const int t = threadIdx.x;
  const ushort_t* wu = (const ushort_t*)W1v;
  unsigned int u = wu[2 * t];
  int e = (u >> 7) & 0xff;
  cnt[t] = (e >= 90 && e <= 140) ? 1 : 0;
  __syncthreads();
  for (int ofs = 128; ofs > 0; ofs >>= 1) {
    if (t < ofs) cnt[t] += cnt[t + ofs];
    __syncthreads();
  }
  if (t == 0) {
    isbf_s = (cnt[0] >= 128) ? 1 : 0;
    *flag = isbf_s;
  }
  __syncthreads();
  const int isbf = isbf_s;
  const ushort_t* epu = (const ushort_t*)end_posv;
  const float* epff = (const float*)end_posv;
  const ushort_t* b2u = (const ushort_t*)b2v;
  const float* b2ff = (const float*)b2v;
  for (int i = t; i < 1024; i += 256) {
    epf[i] = isbf ? bf2f(epu[i]) : epff[i];
    b2f[i] = isbf ? bf2f(b2u[i]) : b2ff[i];
  }
}

// ---------------------------------------------------------------------------
// k_prep: M0[k] = sum_e Wsp[0][e]*W1[e][k]; M1 likewise;
//         hbias[k] = b1[k] + sum_e bsp[e]*W1[e][k]
// ---------------------------------------------------------------------------
__global__ __launch_bounds__(256) void k_prep(
    const void* __restrict__ W_spv, const void* __restrict__ b_spv,
    const void* __restrict__ W1v, const void* __restrict__ b1v,
    const int* __restrict__ flag,
    float* __restrict__ M0, float* __restrict__ M1, float* __restrict__ hbias) {
  const int isbf = *flag;
  const ushort_t* Wspu = (const ushort_t*)W_spv;
  const float* Wspf = (const float*)W_spv;
  const ushort_t* bspu = (const ushort_t*)b_spv;
  const float* bspf = (const float*)b_spv;
  const ushort_t* W1u = (const ushort_t*)W1v;
  const float* W1f = (const float*)W1v;
  const ushort_t* b1u = (const ushort_t*)b1v;
  const float* b1f = (const float*)b1v;
  int k = blockIdx.x * 256 + threadIdx.x;
  float m0 = 0.f, m1 = 0.f, hb = 0.f;
  for (int e = 0; e < ED; ++e) {
    float w = isbf ? bf2f(W1u[e * D1 + k]) : W1f[e * D1 + k];
    float s0 = isbf ? bf2f(Wspu[e]) : Wspf[e];
    float s1 = isbf ? bf2f(Wspu[ED + e]) : Wspf[ED + e];
    float bs = isbf ? bf2f(bspu[e]) : bspf[e];
    m0 += s0 * w;
    m1 += s1 * w;
    hb += bs * w;
  }
  M0[k] = m0;
  M1[k] = m1;
  hbias[k] = hb + (isbf ? bf2f(b1u[k]) : b1f[k]);
}

// ---------------------------------------------------------------------------
// k_hc: hc[j][k] = hbias[k] + sum_h h[j][hh] * W1[64+hh][k]   (bf16 out, 512x8192)
// grid (4, 512), 256 threads; each thread 8 consecutive k
// ---------------------------------------------------------------------------
__global__ __launch_bounds__(256) void k_hc(
    const void* __restrict__ hv, const void* __restrict__ W1v,
    const float* __restrict__ hbias, const int* __restrict__ flag,
    ushort_t* __restrict__ hcb) {
  const int isbf = *flag;
  int j = blockIdx.y;
  int kbase = blockIdx.x * 2048 + threadIdx.x * 8;
  float acc[8];
  {
    float4 t0 = *(const float4*)(hbias + kbase);
    float4 t1 = *(const float4*)(hbias + kbase + 4);
    acc[0] = t0.x; acc[1] = t0.y; acc[2] = t0.z; acc[3] = t0.w;
    acc[4] = t1.x; acc[5] = t1.y; acc[6] = t1.z; acc[7] = t1.w;
  }
  if (isbf) {
    const ushort_t* wrow = (const ushort_t*)W1v + ED * D1 + kbase;
    const ushort_t* hr = (const ushort_t*)hv + j * HD;
#pragma unroll 8
    for (int hh = 0; hh < HD; ++hh) {
      float hvv = bf2f(hr[hh]);
      u32x4 wv = *(const u32x4*)(wrow + hh * D1);
      acc[0] += hvv * bf2f((ushort_t)(wv.x & 0xffffu));
      acc[1] += hvv * bf2f((ushort_t)(wv.x >> 16));
      acc[2] += hvv * bf2f((ushort_t)(wv.y & 0xffffu));
      acc[3] += hvv * bf2f((ushort_t)(wv.y >> 16));
      acc[4] += hvv * bf2f((ushort_t)(wv.z & 0xffffu));
      acc[5] += hvv * bf2f((ushort_t)(wv.z >> 16));
      acc[6] += hvv * bf2f((ushort_t)(wv.w & 0xffffu));
      acc[7] += hvv * bf2f((ushort_t)(wv.w >> 16));
    }
  } else {
    const float* wrow = (const float*)W1v + ED * D1 + kbase;
    const float* hr = (const float*)hv + j * HD;
#pragma unroll 8
    for (int hh = 0; hh < HD; ++hh) {
      float hvv = hr[hh];
      float4 w0 = *(const float4*)(wrow + hh * D1);
      float4 w1 = *(const float4*)(wrow + hh * D1 + 4);
      acc[0] += hvv * w0.x;
      acc[1] += hvv * w0.y;
      acc[2] += hvv * w0.z;
      acc[3] += hvv * w0.w;
      acc[4] += hvv * w1.x;
      acc[5] += hvv * w1.y;
      acc[6] += hvv * w1.z;
      acc[7] += hvv * w1.w;
    }
  }
  u32x4 pk;
  pk.x = f2bf2(acc[0], acc[1]);
  pk.y = f2bf2(acc[2], acc[3]);
  pk.z = f2bf2(acc[4], acc[5]);
  pk.w = f2bf2(acc[6], acc[7]);
  *(u32x4*)(hcb + (size_t)j * D1 + kbase) = pk;
}

// ---------------------------------------------------------------------------
// k_tr: W2T[n][k] = (bf16)W2[k][n]   (8192x1024 -> 1024x8192)
// grid (128, 16): 64(k) x 64(n) tiles, 256 threads
// ---------------------------------------------------------------------------
__global__ __launch_bounds__(256) void k_tr(const void* __restrict__ W2v,
                                            const int* __restrict__ flag,
                                            ushort_t* __restrict__ W2T) {
  __shared__ ushort_t tile[64][72];
  const int isbf = *flag;
  int kt = blockIdx.x, nt = blockIdx.y;
  int t = threadIdx.x;
  int r = t >> 3, c8 = (t & 7) * 8;
#pragma unroll
  for (int i = 0; i < 2; ++i) {
    int row = i * 32 + r;
    size_t base = (size_t)(kt * 64 + row) * BOTN + nt * 64 + c8;
    if (isbf) {
      u32x4 v = *(const u32x4*)((const ushort_t*)W2v + base);
      *(u32x4*)&tile[row][c8] = v;
    } else {
      const float* src = (const float*)W2v + base;
      float4 w0 = *(const float4*)src;
      float4 w1 = *(const float4*)(src + 4);
      u32x4 pk;
      pk.x = f2bf2(w0.x, w0.y);
      pk.y = f2bf2(w0.z, w0.w);
      pk.z = f2bf2(w1.x, w1.y);
      pk.w = f2bf2(w1.z, w1.w);
      *(u32x4*)&tile[row][c8] = pk;
    }
  }
  __syncthreads();
#pragma unroll
  for (int i = 0; i < 2; ++i) {
    int nrow = i * 32 + r;
    union { ushort_t us[8]; u32x4 v; } pk;
#pragma unroll
    for (int jj = 0; jj < 8; ++jj) pk.us[jj] = tile[c8 + jj][nrow];
    *(u32x4*)(W2T + (size_t)(nt * 64 + nrow) * D1 + kt * 64 + c8) = pk.v;
  }
}

// ---------------------------------------------------------------------------
// k_gemm: fused A-gen + GEMM + max-pool epilogue
// rows (s,a,b): m = g*32 + b within block; A[m][k] = relu(hc[s*32+b][k] + r0*M0[k] + r1*M1[k])
// out[s*32+a][n] = relu(max_b (A @ W2T^T) + b2[n])
// BM=128 BN=256 BK=64; grid 512 (mb=bid>>2, nb=bid&3); 4 waves, each 64x128
// ---------------------------------------------------------------------------
__global__ __launch_bounds__(256, 2) void k_gemm(
    const ushort_t* __restrict__ hcb, const float* __restrict__ M0f,
    const float* __restrict__ M1f, const ushort_t* __restrict__ W2T,
    const float* __restrict__ epf, const float* __restrict__ b2f,
    const int* __restrict__ flag, void* __restrict__ outv) {
  __shared__ ushort_t aLds[128 * ASTR];  // [m][k] bf16, padded stride
  __shared__ ushort_t bLds[256 * BSTR];  // [n][k] bf16, padded stride
  __shared__ float2 rrLds[128];

  const int t = threadIdx.x;
  const int w = t >> 6;
  const int lane = t & 63;
  const int mb = blockIdx.x >> 2;  // 0..127
  const int nb = blockIdx.x & 3;   // 0..3
  const int s = mb >> 3;
  const int abase = (mb & 7) * 4;
  const int isbf = *flag;

  if (t < 128) {
    int g = t >> 5, b = t & 31;
    int pa = s * 32 + abase + g, pb = s * 32 + b;
    float r0 = epf[pb * 2] - epf[pa * 2];
    float r1 = epf[pb * 2 + 1] - epf[pa * 2 + 1];
    r0 = fminf(fmaxf(r0, -1.f), 1.f);
    r1 = fminf(fmaxf(r1, -1.f), 1.f);
    rrLds[t] = make_float2(r0, r1);
  }
  __syncthreads();

  const int bq = t >> 3;  // 0..31 : b row this thread generates (also B-stage row)
  const int kc = t & 7;   // 0..7  : 8-col chunk
  float rr0[4], rr1[4];
#pragma unroll
  for (int g = 0; g < 4; ++g) {
    float2 v = rrLds[g * 32 + bq];
    rr0[g] = v.x;
    rr1[g] = v.y;
  }

  const ushort_t* hcRow = hcb + (size_t)(s * 32 + bq) * D1 + kc * 8;
  const float* m0p = M0f + kc * 8;
  const float* m1p = M1f + kc * 8;
  const ushort_t* bGlob = W2T + (size_t)(nb * 256 + bq) * D1 + kc * 8;  // +i*32 rows
  ushort_t* aW = aLds + bq * ASTR + kc * 8;   // + g*32*ASTR
  ushort_t* bW = bLds + bq * BSTR + kc * 8;   // + i*32*BSTR

  f32x4 acc[4][8];
#pragma unroll
  for (int mt = 0; mt < 4; ++mt)
#pragma unroll
    for (int nt = 0; nt < 8; ++nt) acc[mt][nt] = (f32x4){0.f, 0.f, 0.f, 0.f};

  const ushort_t* aR = aLds + ((w & 1) * 64 + (lane & 15)) * ASTR + (lane >> 4) * 8;
  const ushort_t* bR = bLds + ((w >> 1) * 128 + (lane & 15)) * BSTR + (lane >> 4) * 8;

  for (int kk = 0; kk < D1 / 64; ++kk) {
    const int k0 = kk * 64;
    // ---- issue B-tile global loads (latency overlapped by A-gen below) ----
    u32x4 breg[8];
#pragma unroll
    for (int i = 0; i < 8; ++i)
      breg[i] = *(const u32x4*)(bGlob + (size_t)i * 32 * D1 + k0);

    // ---- A-gen: relu(hc + r0*M0 + r1*M1), pack bf16, write LDS ----
    u32x4 hv = *(const u32x4*)(hcRow + k0);
    float h0 = bf2f((ushort_t)(hv.x & 0xffffu)), h1 = bf2f((ushort_t)(hv.x >> 16));
    float h2 = bf2f((ushort_t)(hv.y & 0xffffu)), h3 = bf2f((ushort_t)(hv.y >> 16));
    float h4 = bf2f((ushort_t)(hv.z & 0xffffu)), h5 = bf2f((ushort_t)(hv.z >> 16));
    float h6 = bf2f((ushort_t)(hv.w & 0xffffu)), h7 = bf2f((ushort_t)(hv.w >> 16));
    float4 a0 = *(const float4*)(m0p + k0);
    float4 a1 = *(const float4*)(m0p + k0 + 4);
    float4 c0 = *(const float4*)(m1p + k0);
    float4 c1 = *(const float4*)(m1p + k0 + 4);
#pragma unroll
    for (int g = 0; g < 4; ++g) {
      float r0 = rr0[g], r1 = rr1[g];
      float v0 = fmaxf(h0 + r0 * a0.x + r1 * c0.x, 0.f);
      float v1 = fmaxf(h1 + r0 * a0.y + r1 * c0.y, 0.f);
      float v2 = fmaxf(h2 + r0 * a0.z + r1 * c0.z, 0.f);
      float v3 = fmaxf(h3 + r0 * a0.w + r1 * c0.w, 0.f);
      float v4 = fmaxf(h4 + r0 * a1.x + r1 * c1.x, 0.f);
      float v5 = fmaxf(h5 + r0 * a1.y + r1 * c1.y, 0.f);
      float v6 = fmaxf(h6 + r0 * a1.z + r1 * c1.z, 0.f);
      float v7 = fmaxf(h7 + r0 * a1.w + r1 * c1.w, 0.f);
      u32x4 pk;
      pk.x = f2bf2(v0, v1);
      pk.y = f2bf2(v2, v3);
      pk.z = f2bf2(v4, v5);
      pk.w = f2bf2(v6, v7);
      *(u32x4*)(aW + g * 32 * ASTR) = pk;
    }

    // ---- store staged B tile to LDS ----
#pragma unroll
    for (int i = 0; i < 8; ++i)
      *(u32x4*)(bW + i * 32 * BSTR) = breg[i];

    __syncthreads();
    // ---- mfma phase ----
#pragma unroll
    for (int ki = 0; ki < 2; ++ki) {
      bf16x8 af[4], bfr[8];
#pragma unroll
      for (int mt = 0; mt < 4; ++mt)
        af[mt] = *(const bf16x8*)(aR + mt * 16 * ASTR + ki * 32);
#pragma unroll
      for (int nt = 0; nt < 8; ++nt)
        bfr[nt] = *(const bf16x8*)(bR + nt * 16 * BSTR + ki * 32);
#pragma unroll
      for (int mt = 0; mt < 4; ++mt)
#pragma unroll
        for (int nt = 0; nt < 8; ++nt)
          acc[mt][nt] = __builtin_amdgcn_mfma_f32_16x16x32_bf16(af[mt], bfr[nt], acc[mt][nt], 0, 0, 0);
    }
    __syncthreads();
  }

  // ---- epilogue: max over b (32 rows/group), +b2, relu, store ----
#pragma unroll
  for (int gg = 0; gg < 2; ++gg) {
    int g = (w & 1) * 2 + gg;
    int orow = s * 32 + abase + g;
#pragma unroll
    for (int nt = 0; nt < 8; ++nt) {
      f32x4 x0 = acc[2 * gg][nt], x1 = acc[2 * gg + 1][nt];
      float v = fmaxf(fmaxf(fmaxf(x0.x, x0.y), fmaxf(x0.z, x0.w)),
                      fmaxf(fmaxf(x1.x, x1.y), fmaxf(x1.z, x1.w)));
      v = fmaxf(v, __shfl_xor(v, 16, 64));
      v = fmaxf(v, __shfl_xor(v, 32, 64));
      if (lane < 16) {
        int col = nb * 256 + (w >> 1) * 128 + nt * 16 + lane;
        float o = fmaxf(v + b2f[col], 0.f);
        if (isbf)
          ((ushort_t*)outv)[(size_t)orow * BOTN + col] = f2bf(o);
        else
          ((float*)outv)[(size_t)orow * BOTN + col] = o;
      }
    }
  }
}

extern "C" void kernel_launch(void* const* d_in, const int* in_sizes, int n_in,
                              void* d_out, int out_size, void* d_ws, size_t ws_size,
                              hipStream_t stream) {
  (void)in_sizes; (void)n_in; (void)out_size; (void)ws_size;
  const void* h_states = d_in[0];
  const void* end_pos = d_in[1];
  // d_in[2] rel_pos: unused by reference; d_in[3] seq_start_end: fixed equal scenes
  const void* W_sp = d_in[4];
  const void* b_sp = d_in[5];
  const void* W1 = d_in[6];
  const void* b1 = d_in[7];
  const void* W2 = d_in[8];
  const void* b2 = d_in[9];

  char* ws = (char*)d_ws;
  ushort_t* hcb = (ushort_t*)ws;                         // 8 MB  (512x8192 bf16)
  ushort_t* W2T = (ushort_t*)(ws + (8u << 20));          // 16 MB (1024x8192 bf16)
  float* M0f = (float*)(ws + (24u << 20));               // 32 KB
  float* M1f = (float*)(ws + (24u << 20) + 32768);       // 32 KB
  float* hbias = (float*)(ws + (24u << 20) + 65536);     // 32 KB
  float* epf = (float*)(ws + (24u << 20) + 98304);       // 4 KB
  float* b2f = (float*)(ws + (24u << 20) + 102400);      // 4 KB
  int* flag = (int*)(ws + (24u << 20) + 106496);         // 4 B

  k_detect<<<dim3(1), dim3(256), 0, stream>>>(W1, end_pos, b2, flag, epf, b2f);
  k_prep<<<dim3(32), dim3(256), 0, stream>>>(W_sp, b_sp, W1, b1, flag, M0f, M1f, hbias);
  k_hc<<<dim3(4, 512), dim3(256), 0, stream>>>(h_states, W1, hbias, flag, hcb);
  k_tr<<<dim3(128, 16), dim3(256), 0, stream>>>(W2, flag, W2T);
  k_gemm<<<dim3(512), dim3(256), 0, stream>>>(hcb, M0f, M1f, W2T, epf, b2f, flag, d_out);
}

// Round 6
// 447.608 us; speedup vs baseline: 1.0663x; 1.0663x over previous
//
#include <hip/hip_runtime.h>
#include <stdint.h>

#define NSCENE 16
#define NPED 32
#define NB_TOT 512
#define HD 64
#define ED 64
#define D1 8192
#define BOTN 1024
#define ASTR 72  // A-tile LDS row stride in shorts (144B): 16B-aligned, bank-rotating

typedef unsigned short ushort_t;
typedef __attribute__((ext_vector_type(4))) float f32x4;
typedef __attribute__((ext_vector_type(8))) __bf16 bf16x8;  // gfx950 mfma operand (V8y)
typedef __attribute__((ext_vector_type(4))) unsigned int u32x4;

__device__ __forceinline__ float bf2f(ushort_t u) {
  union { unsigned int i; float f; } x;
  x.i = ((unsigned int)u) << 16;
  return x.f;
}

__device__ __forceinline__ ushort_t f2bf(float f) {
  union { float f; unsigned int i; } x;
  x.f = f;
  unsigned int u = x.i + 0x7fffu + ((x.i >> 16) & 1u);
  return (ushort_t)(u >> 16);
}

// pack two f32 -> two bf16 (lo in bits [15:0]) — portable RNE
__device__ __forceinline__ unsigned int f2bf2(float lo, float hi) {
  return (unsigned int)f2bf(lo) | ((unsigned int)f2bf(hi) << 16);
}

// async global->LDS DMA, 16B/lane. Casts go through integers (always-legal
// reinterpret) to avoid any direct addrspace pointer-cast build hazard.
// HW rule: LDS dest = wave-uniform base + lane*16 — caller must arrange that.
__device__ __forceinline__ void async_load16(const void* g, void* l) {
  __builtin_amdgcn_global_load_lds(
      (const __attribute__((address_space(1))) unsigned int*)(unsigned long long)g,
      (__attribute__((address_space(3))) unsigned int*)(unsigned int)(unsigned long long)l,
      16, 0, 0);
}

// ---------------------------------------------------------------------------
// k_detect: decide whether float inputs are fp32 (expected) or bf16.
// Also produce canonical fp32 copies of end_pos and b2.
// ---------------------------------------------------------------------------
__global__ __launch_bounds__(256) void k_detect(
    const void* __restrict__ W1v, const void* __restrict__ end_posv,
    const void* __restrict__ b2v, int* __restrict__ flag,
    float* __restrict__ epf, float* __restrict__ b2f) {
  __shared__ int cnt[256];
  __shared__ int isbf_s;
  const int t = threadIdx.x;
  const ushort_t* wu = (const ushort_t*)W1v;
  unsigned int u = wu[2 * t];
  int e = (u >> 7) & 0xff;
  cnt[t] = (e >= 90 && e <= 140) ? 1 : 0;
  __syncthreads();
  for (int ofs = 128; ofs > 0; ofs >>= 1) {
    if (t < ofs) cnt[t] += cnt[t + ofs];
    __syncthreads();
  }
  if (t == 0) {
    isbf_s = (cnt[0] >= 128) ? 1 : 0;
    *flag = isbf_s;
  }
  __syncthreads();
  const int isbf = isbf_s;
  const ushort_t* epu = (const ushort_t*)end_posv;
  const float* epff = (const float*)end_posv;
  const ushort_t* b2u = (const ushort_t*)b2v;
  const float* b2ff = (const float*)b2v;
  for (int i = t; i < 1024; i += 256) {
    epf[i] = isbf ? bf2f(epu[i]) : epff[i];
    b2f[i] = isbf ? bf2f(b2u[i]) : b2ff[i];
  }
}

// ---------------------------------------------------------------------------
// k_prep: M0[k] = sum_e Wsp[0][e]*W1[e][k]; M1 likewise;
//         hbias[k] = b1[k] + sum_e bsp[e]*W1[e][k]
// ---------------------------------------------------------------------------
__global__ __launch_bounds__(256) void k_prep(
    const void* __restrict__ W_spv, const void* __restrict__ b_spv,
    const void* __restrict__ W1v, const void* __restrict__ b1v,
    const int* __restrict__ flag,
    float* __restrict__ M0, float* __restrict__ M1, float* __restrict__ hbias) {
  const int isbf = *flag;
  const ushort_t* Wspu = (const ushort_t*)W_spv;
  const float* Wspf = (const float*)W_spv;
  const ushort_t* bspu = (const ushort_t*)b_spv;
  const float* bspf = (const float*)b_spv;
  const ushort_t* W1u = (const ushort_t*)W1v;
  const float* W1f = (const float*)W1v;
  const ushort_t* b1u = (const ushort_t*)b1v;
  const float* b1f = (const float*)b1v;
  int k = blockIdx.x * 256 + threadIdx.x;
  float m0 = 0.f, m1 = 0.f, hb = 0.f;
  for (int e = 0; e < ED; ++e) {
    float w = isbf ? bf2f(W1u[e * D1 + k]) : W1f[e * D1 + k];
    float s0 = isbf ? bf2f(Wspu[e]) : Wspf[e];
    float s1 = isbf ? bf2f(Wspu[ED + e]) : Wspf[ED + e];
    float bs = isbf ? bf2f(bspu[e]) : bspf[e];
    m0 += s0 * w;
    m1 += s1 * w;
    hb += bs * w;
  }
  M0[k] = m0;
  M1[k] = m1;
  hbias[k] = hb + (isbf ? bf2f(b1u[k]) : b1f[k]);
}

// ---------------------------------------------------------------------------
// k_hc: hc[j][k] = hbias[k] + sum_h h[j][hh] * W1[64+hh][k]   (bf16 out, 512x8192)
// ---------------------------------------------------------------------------
__global__ __launch_bounds__(256) void k_hc(
    const void* __restrict__ hv, const void* __restrict__ W1v,
    const float* __restrict__ hbias, const int* __restrict__ flag,
    ushort_t* __restrict__ hcb) {
  const int isbf = *flag;
  int j = blockIdx.y;
  int kbase = blockIdx.x * 2048 + threadIdx.x * 8;
  float acc[8];
  {
    float4 t0 = *(const float4*)(hbias + kbase);
    float4 t1 = *(const float4*)(hbias + kbase + 4);
    acc[0] = t0.x; acc[1] = t0.y; acc[2] = t0.z; acc[3] = t0.w;
    acc[4] = t1.x; acc[5] = t1.y; acc[6] = t1.z; acc[7] = t1.w;
  }
  if (isbf) {
    const ushort_t* wrow = (const ushort_t*)W1v + ED * D1 + kbase;
    const ushort_t* hr = (const ushort_t*)hv + j * HD;
#pragma unroll 8
    for (int hh = 0; hh < HD; ++hh) {
      float hvv = bf2f(hr[hh]);
      u32x4 wv = *(const u32x4*)(wrow + hh * D1);
      acc[0] += hvv * bf2f((ushort_t)(wv.x & 0xffffu));
      acc[1] += hvv * bf2f((ushort_t)(wv.x >> 16));
      acc[2] += hvv * bf2f((ushort_t)(wv.y & 0xffffu));
      acc[3] += hvv * bf2f((ushort_t)(wv.y >> 16));
      acc[4] += hvv * bf2f((ushort_t)(wv.z & 0xffffu));
      acc[5] += hvv * bf2f((ushort_t)(wv.z >> 16));
      acc[6] += hvv * bf2f((ushort_t)(wv.w & 0xffffu));
      acc[7] += hvv * bf2f((ushort_t)(wv.w >> 16));
    }
  } else {
    const float* wrow = (const float*)W1v + ED * D1 + kbase;
    const float* hr = (const float*)hv + j * HD;
#pragma unroll 8
    for (int hh = 0; hh < HD; ++hh) {
      float hvv = hr[hh];
      float4 w0 = *(const float4*)(wrow + hh * D1);
      float4 w1 = *(const float4*)(wrow + hh * D1 + 4);
      acc[0] += hvv * w0.x;
      acc[1] += hvv * w0.y;
      acc[2] += hvv * w0.z;
      acc[3] += hvv * w0.w;
      acc[4] += hvv * w1.x;
      acc[5] += hvv * w1.y;
      acc[6] += hvv * w1.z;
      acc[7] += hvv * w1.w;
    }
  }
  u32x4 pk;
  pk.x = f2bf2(acc[0], acc[1]);
  pk.y = f2bf2(acc[2], acc[3]);
  pk.z = f2bf2(acc[4], acc[5]);
  pk.w = f2bf2(acc[6], acc[7]);
  *(u32x4*)(hcb + (size_t)j * D1 + kbase) = pk;
}

// ---------------------------------------------------------------------------
// k_tr: W2T[n][k] = (bf16)W2[k][n]   (8192x1024 -> 1024x8192)
// ---------------------------------------------------------------------------
__global__ __launch_bounds__(256) void k_tr(const void* __restrict__ W2v,
                                            const int* __restrict__ flag,
                                            ushort_t* __restrict__ W2T) {
  __shared__ ushort_t tile[64][72];
  const int isbf = *flag;
  int kt = blockIdx.x, nt = blockIdx.y;
  int t = threadIdx.x;
  int r = t >> 3, c8 = (t & 7) * 8;
#pragma unroll
  for (int i = 0; i < 2; ++i) {
    int row = i * 32 + r;
    size_t base = (size_t)(kt * 64 + row) * BOTN + nt * 64 + c8;
    if (isbf) {
      u32x4 v = *(const u32x4*)((const ushort_t*)W2v + base);
      *(u32x4*)&tile[row][c8] = v;
    } else {
      const float* src = (const float*)W2v + base;
      float4 w0 = *(const float4*)src;
      float4 w1 = *(const float4*)(src + 4);
      u32x4 pk;
      pk.x = f2bf2(w0.x, w0.y);
      pk.y = f2bf2(w0.z, w0.w);
      pk.z = f2bf2(w1.x, w1.y);
      pk.w = f2bf2(w1.z, w1.w);
      *(u32x4*)&tile[row][c8] = pk;
    }
  }
  __syncthreads();
#pragma unroll
  for (int i = 0; i < 2; ++i) {
    int nrow = i * 32 + r;
    union { ushort_t us[8]; u32x4 v; } pk;
#pragma unroll
    for (int jj = 0; jj < 8; ++jj) pk.us[jj] = tile[c8 + jj][nrow];
    *(u32x4*)(W2T + (size_t)(nt * 64 + nrow) * D1 + kt * 64 + c8) = pk.v;
  }
}

// ---------------------------------------------------------------------------
// k_gemm: fused A-gen + GEMM + max-pool epilogue
// BM=64 BN=512 BK=64; grid 512: nb=bid&1 (XCD-aligned), mb=bid>>1 (0..255)
// tile m-row = g*32+b (g in 0..1); A[m][k] = relu(hc[s*32+b][k]+r0*M0[k]+r1*M1[k])
// out[s*32+abase+g][n] = relu(max_b C + b2[n]); 4 waves, each 64m x 128n
// B tile: DMA (global_load_lds w16) into unpadded [512][64] LDS with XOR
// swizzle applied on the GLOBAL fetch side: slot sl of row r holds global
// chunk sl^(r&7); readers fetch slot ck^(r&7).
// ---------------------------------------------------------------------------
__global__ __launch_bounds__(256, 2) void k_gemm(
    const ushort_t* __restrict__ hcb, const float* __restrict__ M0f,
    const float* __restrict__ M1f, const ushort_t* __restrict__ W2T,
    const float* __restrict__ epf, const float* __restrict__ b2f,
    const int* __restrict__ flag, void* __restrict__ outv) {
  __shared__ ushort_t aLds[64 * ASTR];   // 9.2 KB, padded
  __shared__ ushort_t bLds[512 * 64];    // 64 KB, unpadded (DMA dest), swizzled
  __shared__ float2 rrLds[64];

  const int t = threadIdx.x;
  const int w = t >> 6;
  const int lane = t & 63;
  const int nb = blockIdx.x & 1;
  const int mb = blockIdx.x >> 1;  // 0..255
  const int s = mb >> 4;
  const int abase = (mb & 15) * 2;
  const int isbf = *flag;

  if (t < 64) {
    int g = t >> 5, b = t & 31;
    int pa = s * 32 + abase + g, pb = s * 32 + b;
    float r0 = epf[pb * 2] - epf[pa * 2];
    float r1 = epf[pb * 2 + 1] - epf[pa * 2 + 1];
    r0 = fminf(fmaxf(r0, -1.f), 1.f);
    r1 = fminf(fmaxf(r1, -1.f), 1.f);
    rrLds[t] = make_float2(r0, r1);
  }
  __syncthreads();

  const int bq = t >> 3;  // 0..31 : hc row (b) this thread generates
  const int kc = t & 7;   // 0..7  : 8-short chunk within BK
  float rr0[2], rr1[2];
#pragma unroll
  for (int g = 0; g < 2; ++g) {
    float2 v = rrLds[g * 32 + bq];
    rr0[g] = v.x;
    rr1[g] = v.y;
  }

  const ushort_t* hcRow = hcb + (size_t)(s * 32 + bq) * D1 + kc * 8;
  const float* m0p = M0f + kc * 8;
  const float* m1p = M1f + kc * 8;

  // B DMA addressing: lane covers row (i*32 + w*8 + (lane>>3)), LDS slot lane&7,
  // so it must FETCH global chunk (lane&7) ^ (lane>>3).
  const int rowl = w * 8 + (lane >> 3);
  const int chl = (lane & 7) ^ (lane >> 3);
  const ushort_t* bGlob = W2T + (size_t)(nb * 512 + rowl) * D1 + chl * 8;
  ushort_t* bLdsLane = bLds + (size_t)rowl * 64 + (lane & 7) * 8;  // = base_i + lane*16B

  ushort_t* aW = aLds + bq * ASTR + kc * 8;  // + g*32*ASTR

  f32x4 acc[4][8];
#pragma unroll
  for (int mt = 0; mt < 4; ++mt)
#pragma unroll
    for (int nt = 0; nt < 8; ++nt) acc[mt][nt] = (f32x4){0.f, 0.f, 0.f, 0.f};

  const int rl = lane & 15, q = lane >> 4, r7 = rl & 7;
  const ushort_t* aRbase = aLds + rl * ASTR + q * 8;          // + mt*16*ASTR + ki*32
  const ushort_t* bRbase = bLds + (w * 128 + rl) * 64;        // + nt*1024 + slot*8
  const int sl0 = (q ^ r7) * 8;        // ki=0: global chunk q
  const int sl1 = ((q + 4) ^ r7) * 8;  // ki=1: global chunk q+4

  for (int kk = 0; kk < D1 / 64; ++kk) {
    const int k0 = kk * 64;
    // ---- B tile: async DMA global->LDS (16B/lane, 8 rows per issue) ----
#pragma unroll
    for (int i = 0; i < 16; ++i)
      async_load16(bGlob + (size_t)i * 32 * D1 + k0, bLdsLane + i * 32 * 64);

    // ---- A-gen: relu(hc + r0*M0 + r1*M1), pack bf16, write LDS ----
    u32x4 hv = *(const u32x4*)(hcRow + k0);
    float h0 = bf2f((ushort_t)(hv.x & 0xffffu)), h1 = bf2f((ushort_t)(hv.x >> 16));
    float h2 = bf2f((ushort_t)(hv.y & 0xffffu)), h3 = bf2f((ushort_t)(hv.y >> 16));
    float h4 = bf2f((ushort_t)(hv.z & 0xffffu)), h5 = bf2f((ushort_t)(hv.z >> 16));
    float h6 = bf2f((ushort_t)(hv.w & 0xffffu)), h7 = bf2f((ushort_t)(hv.w >> 16));
    float4 a0 = *(const float4*)(m0p + k0);
    float4 a1 = *(const float4*)(m0p + k0 + 4);
    float4 c0 = *(const float4*)(m1p + k0);
    float4 c1 = *(const float4*)(m1p + k0 + 4);
#pragma unroll
    for (int g = 0; g < 2; ++g) {
      float r0 = rr0[g], r1 = rr1[g];
      float v0 = fmaxf(h0 + r0 * a0.x + r1 * c0.x, 0.f);
      float v1 = fmaxf(h1 + r0 * a0.y + r1 * c0.y, 0.f);
      float v2 = fmaxf(h2 + r0 * a0.z + r1 * c0.z, 0.f);
      float v3 = fmaxf(h3 + r0 * a0.w + r1 * c0.w, 0.f);
      float v4 = fmaxf(h4 + r0 * a1.x + r1 * c1.x, 0.f);
      float v5 = fmaxf(h5 + r0 * a1.y + r1 * c1.y, 0.f);
      float v6 = fmaxf(h6 + r0 * a1.z + r1 * c1.z, 0.f);
      float v7 = fmaxf(h7 + r0 * a1.w + r1 * c1.w, 0.f);
      u32x4 pk;
      pk.x = f2bf2(v0, v1);
      pk.y = f2bf2(v2, v3);
      pk.z = f2bf2(v4, v5);
      pk.w = f2bf2(v6, v7);
      *(u32x4*)(aW + g * 32 * ASTR) = pk;
    }
    __syncthreads();  // drains DMA (vmcnt) + A-gen ds_writes

    // ---- mfma phase ----
#pragma unroll
    for (int ki = 0; ki < 2; ++ki) {
      bf16x8 af[4], bfr[8];
#pragma unroll
      for (int mt = 0; mt < 4; ++mt)
        af[mt] = *(const bf16x8*)(aRbase + mt * 16 * ASTR + ki * 32);
      const int slk = ki ? sl1 : sl0;
#pragma unroll
      for (int nt = 0; nt < 8; ++nt)
        bfr[nt] = *(const bf16x8*)(bRbase + nt * 1024 + slk);
#pragma unroll
      for (int mt = 0; mt < 4; ++mt)
#pragma unroll
        for (int nt = 0; nt < 8; ++nt)
          acc[mt][nt] = __builtin_amdgcn_mfma_f32_16x16x32_bf16(af[mt], bfr[nt], acc[mt][nt], 0, 0, 0);
    }
    __syncthreads();
  }

  // ---- epilogue: max over b (32 m-rows per group), +b2, relu, store ----
#pragma unroll
  for (int g = 0; g < 2; ++g) {
    int orow = s * 32 + abase + g;
#pragma unroll
    for (int nt = 0; nt < 8; ++nt) {
      f32x4 x0 = acc[2 * g][nt], x1 = acc[2 * g + 1][nt];
      float v = fmaxf(fmaxf(fmaxf(x0.x, x0.y), fmaxf(x0.z, x0.w)),
                      fmaxf(fmaxf(x1.x, x1.y), fmaxf(x1.z, x1.w)));
      v = fmaxf(v, __shfl_xor(v, 16, 64));
      v = fmaxf(v, __shfl_xor(v, 32, 64));
      if (lane < 16) {
        int col = nb * 512 + w * 128 + nt * 16 + lane;
        float o = fmaxf(v + b2f[col], 0.f);
        if (isbf)
          ((ushort_t*)outv)[(size_t)orow * BOTN + col] = f2bf(o);
        else
          ((float*)outv)[(size_t)orow * BOTN + col] = o;
      }
    }
  }
}

extern "C" void kernel_launch(void* const* d_in, const int* in_sizes, int n_in,
                              void* d_out, int out_size, void* d_ws, size_t ws_size,
                              hipStream_t stream) {
  (void)in_sizes; (void)n_in; (void)out_size; (void)ws_size;
  const void* h_states = d_in[0];
  const void* end_pos = d_in[1];
  // d_in[2] rel_pos: unused by reference; d_in[3] seq_start_end: fixed equal scenes
  const void* W_sp = d_in[4];
  const void* b_sp = d_in[5];
  const void* W1 = d_in[6];
  const void* b1 = d_in[7];
  const void* W2 = d_in[8];
  const void* b2 = d_in[9];

  char* ws = (char*)d_ws;
  ushort_t* hcb = (ushort_t*)ws;                         // 8 MB  (512x8192 bf16)
  ushort_t* W2T = (ushort_t*)(ws + (8u << 20));          // 16 MB (1024x8192 bf16)
  float* M0f = (float*)(ws + (24u << 20));               // 32 KB
  float* M1f = (float*)(ws + (24u << 20) + 32768);       // 32 KB
  float* hbias = (float*)(ws + (24u << 20) + 65536);     // 32 KB
  float* epf = (float*)(ws + (24u << 20) + 98304);       // 4 KB
  float* b2f = (float*)(ws + (24u << 20) + 102400);      // 4 KB
  int* flag = (int*)(ws + (24u << 20) + 106496);         // 4 B

  k_detect<<<dim3(1), dim3(256), 0, stream>>>(W1, end_pos, b2, flag, epf, b2f);
  k_prep<<<dim3(32), dim3(256), 0, stream>>>(W_sp, b_sp, W1, b1, flag, M0f, M1f, hbias);
  k_hc<<<dim3(4, 512), dim3(256), 0, stream>>>(h_states, W1, hbias, flag, hcb);
  k_tr<<<dim3(128, 16), dim3(256), 0, stream>>>(W2, flag, W2T);
  k_gemm<<<dim3(512), dim3(256), 0, stream>>>(hcb, M0f, M1f, W2T, epf, b2f, flag, d_out);
}